// Round 16
// baseline (474.234 us; speedup 1.0000x reference)
//
#include <hip/hip_runtime.h>
#include <math.h>

#define B  128
#define L  196
#define F2 512
#define T  32
#define D  256
#define H  512
#define H4 2048
#define KCAT 1024     // ctx(512) + h(512); word part precomputed
#define KS 4
#define KCHUNK 256    // KCAT/KS

typedef __attribute__((ext_vector_type(8))) short bf16x8;
typedef __attribute__((ext_vector_type(4))) float f32x4;

__device__ __forceinline__ float sigf(float x) { return 1.0f / (1.0f + expf(-x)); }
__device__ __forceinline__ unsigned short f2bf(float x) {
    unsigned u = __float_as_uint(x);
    u += 0x7FFF + ((u >> 16) & 1);
    return (unsigned short)(u >> 16);
}
__device__ __forceinline__ float bf2f(unsigned short s) {
    return __uint_as_float(((unsigned)s) << 16);
}
__device__ __forceinline__ float wred_sum(float v) {
    for (int o = 32; o > 0; o >>= 1) v += __shfl_down(v, o);
    return v;
}

// ---------- setup ----------

__global__ void k_prep2(const float* __restrict__ X, const float* __restrict__ w_a,
                        const float* __restrict__ b_a, unsigned short* __restrict__ Xb,
                        float* __restrict__ fscore, float* __restrict__ fmpart) {
    __shared__ float sp[8][512];
    int b = blockIdx.x, g = blockIdx.y, tid = threadIdx.x;
    int rowi = tid >> 5, lane32 = tid & 31;
    int f0 = tid * 2;
    float2 acc = make_float2(0.f, 0.f);
    for (int s = 0; s < 4; ++s) {
        int li = s * 8 + rowi;
        float4 part[4];
        if (li < 28) {
            size_t row = (size_t)b * L + g * 28 + li;
            const float* src = X + row * F2;
            unsigned short* dst = Xb + row * F2;
            float sc = 0.f;
            #pragma unroll
            for (int j = 0; j < 4; ++j) {
                int f = j * 128 + lane32 * 4;
                float4 v = *(const float4*)(src + f);
                float4 w = *(const float4*)(w_a + f);
                sc += v.x * w.x + v.y * w.y + v.z * w.z + v.w * w.w;
                part[j] = v;
                ushort4 u;
                u.x = f2bf(v.x); u.y = f2bf(v.y); u.z = f2bf(v.z); u.w = f2bf(v.w);
                *(ushort4*)(dst + f) = u;
            }
            for (int o = 16; o > 0; o >>= 1) sc += __shfl_down(sc, o, 32);
            if (lane32 == 0) fscore[row] = sc + b_a[0];
        } else {
            #pragma unroll
            for (int j = 0; j < 4; ++j) part[j] = make_float4(0.f, 0.f, 0.f, 0.f);
        }
        __syncthreads();
        #pragma unroll
        for (int j = 0; j < 4; ++j)
            *(float4*)&sp[rowi][j * 128 + lane32 * 4] = part[j];
        __syncthreads();
        #pragma unroll
        for (int r = 0; r < 8; ++r) { acc.x += sp[r][f0]; acc.y += sp[r][f0 + 1]; }
    }
    *(float2*)&fmpart[((size_t)b * 7 + g) * 512 + f0] = acc;
}

__global__ void k_mred(const float* __restrict__ fmpart, unsigned short* __restrict__ fmb) {
    int b = blockIdx.x, tid = threadIdx.x;
    int f0 = tid * 2;
    float2 acc = make_float2(0.f, 0.f);
    #pragma unroll
    for (int g = 0; g < 7; ++g) {
        float2 v = *(const float2*)&fmpart[((size_t)b * 7 + g) * 512 + f0];
        acc.x += v.x; acc.y += v.y;
    }
    ushort2 u; u.x = f2bf(acc.x * (1.0f / L)); u.y = f2bf(acc.y * (1.0f / L));
    *(ushort2*)(fmb + (size_t)b * F2 + f0) = u;
}

// all 5 transpose-cast jobs in one kernel (byte-exact r15). grid (16, 32, 5).
__global__ void k_trAll(const float* __restrict__ k_w, const float* __restrict__ r_w,
                        const float* __restrict__ w_h, const float* __restrict__ w_c,
                        unsigned short* __restrict__ WcatT, unsigned short* __restrict__ wT,
                        unsigned short* __restrict__ wiT) {
    int job = blockIdx.z;
    if (job == 2 && blockIdx.x >= 8) return;
    if (job >= 3 && blockIdx.y >= 8) return;
    const float* src; unsigned short* dstBase; int srcLD, dstLD, colOff;
    if (job == 0)      { src = k_w + (size_t)256 * H4; dstBase = WcatT; srcLD = H4;  dstLD = KCAT; colOff = 0; }
    else if (job == 1) { src = r_w;  dstBase = WcatT;                   srcLD = H4;  dstLD = KCAT; colOff = 512; }
    else if (job == 2) { src = k_w;  dstBase = wT;                      srcLD = H4;  dstLD = 256;  colOff = 0; }
    else if (job == 3) { src = w_h;  dstBase = wiT;                     srcLD = 512; dstLD = 512;  colOff = 0; }
    else               { src = w_c;  dstBase = wiT + (size_t)512 * 512; srcLD = 512; dstLD = 512;  colOff = 0; }
    __shared__ float Ls[32][65];
    int r0 = blockIdx.x * 32, c0 = blockIdx.y * 64;
    int tid = threadIdx.x;
    int r = tid >> 3, c8 = (tid & 7) * 8;
    const float* s = src + (size_t)(r0 + r) * srcLD + c0 + c8;
    #pragma unroll
    for (int j = 0; j < 8; ++j) Ls[r][c8 + j] = s[j];
    __syncthreads();
    int cc = tid >> 2, q = tid & 3;
    unsigned short tmp[8];
    #pragma unroll
    for (int j = 0; j < 8; ++j) tmp[j] = f2bf(Ls[q * 8 + j][cc]);
    *(float4*)(dstBase + (size_t)(c0 + cc) * dstLD + colOff + r0 + q * 8) = *(float4*)tmp;
}

// ---------- combined one-time GEMMs, re-tiled ----------
// bid < 4096: wgemm 64x32 tiles (k_gemm32-clone geometry, 16x more parallelism
// than r15's 128x128 version; K-chain order identical -> bit-identical wpart).
// bid >= 4096: init-state GEMM (8 blocks, body byte-exact r15).
__global__ __launch_bounds__(256) void k_wi(
    const float* __restrict__ word,           // [4096][256] fp32
    const unsigned short* __restrict__ wT,    // [2048][256] bf16
    float* __restrict__ wpart,                // [4096][2048] fp32
    const unsigned short* __restrict__ A,     // fm_bf16 [128][512]
    const unsigned short* __restrict__ Bt,    // wiT [1024][512]
    const float* __restrict__ b_h, const float* __restrict__ b_c,
    unsigned short* __restrict__ Abuf0, float* __restrict__ cbuf) {
    __shared__ short As[128 * 64];
    __shared__ short Bs[128 * 64];
    int tid = threadIdx.x;
    int bid = blockIdx.x;
    int wave = tid >> 6, lane = tid & 63;
    int l15 = lane & 15, l4 = lane >> 4;

    if (bid < 4096) {
        // ---- word GEMM: 64x32 tile. M=4096, N=2048, K=256 ----
        int rowbase = (bid >> 6) * 64;        // 64 m-tiles of 64 rows
        int nbase = (bid & 63) * 32;          // 64 n-tiles of 32 cols
        int wm = (wave & 1) * 32, wn = (wave >> 1) * 16;

        f32x4 acc[2];
        acc[0] = (f32x4){0.f, 0.f, 0.f, 0.f};
        acc[1] = (f32x4){0.f, 0.f, 0.f, 0.f};

        for (int it = 0; it < 4; ++it) {
            int kbase = it * 64;
            #pragma unroll
            for (int p = 0; p < 2; ++p) {
                int idx = p * 256 + tid;
                int row = idx >> 3, q = idx & 7;
                int k = kbase + q * 8;
                const float* ap = word + (size_t)(rowbase + row) * 256 + k;
                float4 v0 = *(const float4*)ap;
                float4 v1 = *(const float4*)(ap + 4);
                unsigned short tmp[8];
                tmp[0] = f2bf(v0.x); tmp[1] = f2bf(v0.y); tmp[2] = f2bf(v0.z); tmp[3] = f2bf(v0.w);
                tmp[4] = f2bf(v1.x); tmp[5] = f2bf(v1.y); tmp[6] = f2bf(v1.z); tmp[7] = f2bf(v1.w);
                *(float4*)&As[row * 64 + ((q ^ (row & 7)) << 3)] = *(float4*)tmp;
            }
            {
                int row = tid >> 3, q = tid & 7;
                float4 w = *(const float4*)(wT + (size_t)(nbase + row) * 256 + kbase + q * 8);
                *(float4*)&Bs[row * 64 + ((q ^ (row & 7)) << 3)] = w;
            }
            __syncthreads();
            #pragma unroll
            for (int ks2 = 0; ks2 < 2; ++ks2) {
                int q = ks2 * 4 + l4;
                bf16x8 a[2], bb;
                #pragma unroll
                for (int fm = 0; fm < 2; ++fm) {
                    int ar = wm + fm * 16 + l15;
                    a[fm] = *(const bf16x8*)&As[ar * 64 + ((q ^ (ar & 7)) << 3)];
                }
                {
                    int br = wn + l15;
                    bb = *(const bf16x8*)&Bs[br * 64 + ((q ^ (br & 7)) << 3)];
                }
                #pragma unroll
                for (int fm = 0; fm < 2; ++fm)
                    acc[fm] = __builtin_amdgcn_mfma_f32_16x16x32_bf16(a[fm], bb, acc[fm], 0, 0, 0);
            }
            __syncthreads();
        }
        #pragma unroll
        for (int fm = 0; fm < 2; ++fm)
            #pragma unroll
            for (int j = 0; j < 4; ++j) {
                int m = rowbase + wm + fm * 16 + l4 * 4 + j;
                wpart[(size_t)m * H4 + nbase + wn + l15] = acc[fm][j];
            }
        return;
    }

    // ---- init-state GEMM: M=128, K=512, N=1024 (8 tail blocks) ----
    int nbase = (bid - 4096) * 128;
    int wm = (wave >> 1) * 64, wn = (wave & 1) * 64;

    f32x4 acc[4][4];
    #pragma unroll
    for (int i = 0; i < 4; ++i)
        #pragma unroll
        for (int j = 0; j < 4; ++j) acc[i][j] = (f32x4){0.f, 0.f, 0.f, 0.f};

    for (int it = 0; it < 8; ++it) {
        int kbase = it * 64;
        #pragma unroll
        for (int ch = 0; ch < 4; ++ch) {
            int idx = ch * 256 + tid;
            int row = idx >> 3, q = idx & 7;
            int k = kbase + q * 8;
            float4 v = *(const float4*)(A + (size_t)row * 512 + k);
            *(float4*)&As[row * 64 + ((q ^ (row & 7)) << 3)] = v;
            float4 w = *(const float4*)(Bt + (size_t)(nbase + row) * 512 + k);
            *(float4*)&Bs[row * 64 + ((q ^ (row & 7)) << 3)] = w;
        }
        __syncthreads();
        #pragma unroll
        for (int ks = 0; ks < 2; ++ks) {
            bf16x8 a[4], b[4];
            #pragma unroll
            for (int f = 0; f < 4; ++f) {
                int ar = wm + f * 16 + l15;
                int q = ks * 4 + l4;
                a[f] = *(const bf16x8*)&As[ar * 64 + ((q ^ (ar & 7)) << 3)];
                int br = wn + f * 16 + l15;
                b[f] = *(const bf16x8*)&Bs[br * 64 + ((q ^ (br & 7)) << 3)];
            }
            #pragma unroll
            for (int fm = 0; fm < 4; ++fm)
                #pragma unroll
                for (int fn = 0; fn < 4; ++fn)
                    acc[fm][fn] = __builtin_amdgcn_mfma_f32_16x16x32_bf16(a[fm], b[fn], acc[fm][fn], 0, 0, 0);
        }
        __syncthreads();
    }
    #pragma unroll
    for (int fm = 0; fm < 4; ++fm)
        #pragma unroll
        for (int j = 0; j < 4; ++j) {
            int m = wm + fm * 16 + l4 * 4 + j;
            #pragma unroll
            for (int fn = 0; fn < 4; ++fn) {
                int gn = nbase + wn + fn * 16 + l15;
                float v = acc[fm][fn][j];
                if (gn < 512) Abuf0[(size_t)m * 1024 + 512 + gn] = f2bf(tanhf(v + b_h[gn]));
                else          cbuf[(size_t)m * 512 + gn - 512] = tanhf(v + b_c[gn - 512]);
            }
        }
}

// ---------- per-step gates GEMM: K=1024, 64x32 tiles, 512 blocks (byte-exact r13-r15) ----------
__global__ __launch_bounds__(256) void k_gemm32(
    const unsigned short* __restrict__ Abuf,
    const unsigned short* __restrict__ WcatT,  // [2048][1024]
    float* __restrict__ zpart) {
    __shared__ short As[64 * 64];
    __shared__ short Bs[32 * 64];
    int tid = threadIdx.x;
    int bid = blockIdx.x;
    int ksb = bid >> 7, rem = bid & 127;
    int rowbase = (rem >> 6) * 64, nbase = (rem & 63) * 32;
    int wave = tid >> 6, lane = tid & 63;
    int wm = (wave & 1) * 32, wn = (wave >> 1) * 16;
    int l15 = lane & 15, l4 = lane >> 4;

    f32x4 acc[2];
    acc[0] = (f32x4){0.f, 0.f, 0.f, 0.f};
    acc[1] = (f32x4){0.f, 0.f, 0.f, 0.f};

    for (int it = 0; it < KCHUNK / 64; ++it) {
        int kbase = ksb * KCHUNK + it * 64;
        #pragma unroll
        for (int p = 0; p < 2; ++p) {
            int idx = p * 256 + tid;
            int row = idx >> 3, q = idx & 7;
            int k = kbase + q * 8;
            float4 v = *(const float4*)(Abuf + (size_t)(rowbase + row) * 1024 + k);
            *(float4*)&As[row * 64 + ((q ^ (row & 7)) << 3)] = v;
        }
        {
            int row = tid >> 3, q = tid & 7;
            float4 w = *(const float4*)(WcatT + (size_t)(nbase + row) * KCAT + kbase + q * 8);
            *(float4*)&Bs[row * 64 + ((q ^ (row & 7)) << 3)] = w;
        }
        __syncthreads();
        #pragma unroll
        for (int ks2 = 0; ks2 < 2; ++ks2) {
            int q = ks2 * 4 + l4;
            bf16x8 a[2], bb;
            #pragma unroll
            for (int fm = 0; fm < 2; ++fm) {
                int ar = wm + fm * 16 + l15;
                a[fm] = *(const bf16x8*)&As[ar * 64 + ((q ^ (ar & 7)) << 3)];
            }
            {
                int br = wn + l15;
                bb = *(const bf16x8*)&Bs[br * 64 + ((q ^ (br & 7)) << 3)];
            }
            #pragma unroll
            for (int fm = 0; fm < 2; ++fm)
                acc[fm] = __builtin_amdgcn_mfma_f32_16x16x32_bf16(a[fm], bb, acc[fm], 0, 0, 0);
        }
        __syncthreads();
    }
    float* zp = zpart + (size_t)ksb * B * H4;
    #pragma unroll
    for (int fm = 0; fm < 2; ++fm)
        #pragma unroll
        for (int j = 0; j < 4; ++j) {
            int m = rowbase + wm + fm * 16 + l4 * 4 + j;
            zp[(size_t)m * H4 + nbase + wn + l15] = acc[fm][j];
        }
}

// ---------- fused cell + attention. grid (B, 4), 256 thr (byte-exact r14/r15) ----------
__global__ __launch_bounds__(256) void k_step4(
    const float* __restrict__ zpart, const float* __restrict__ wpart,
    const float* __restrict__ bias,
    const float* __restrict__ cb_cur, float* __restrict__ cb_nxt,
    unsigned short* __restrict__ Abuf,
    const unsigned short* __restrict__ Xb, const float* __restrict__ fscore,
    const float* __restrict__ w_a_h,
    float* __restrict__ out_h, float* __restrict__ out_m, float* __restrict__ out_a,
    int t_next) {
    __shared__ float red[8];
    __shared__ float sal[200];
    __shared__ float sp2[4][64][2];
    int b = blockIdx.x, quarter = blockIdx.y, tid = threadIdx.x;
    int lane = tid & 63, wid = tid >> 6;
    int n0 = tid * 2;
    float hp;
    if (t_next > 0) {
        const float* wp = wpart + ((size_t)b * T + (t_next - 1)) * H4;
        float2 z[4];
        #pragma unroll
        for (int g = 0; g < 4; ++g) {
            float2 bz = *(const float2*)(bias + g * H + n0);
            float2 wz = *(const float2*)(wp + g * H + n0);
            z[g].x = bz.x + wz.x; z[g].y = bz.y + wz.y;
        }
        #pragma unroll
        for (int ks = 0; ks < KS; ++ks) {
            const float* zp = zpart + ((size_t)ks * B + b) * H4;
            #pragma unroll
            for (int g = 0; g < 4; ++g) {
                float2 v = *(const float2*)(zp + g * H + n0);
                z[g].x += v.x; z[g].y += v.y;
            }
        }
        float2 cv = *(const float2*)(cb_cur + (size_t)b * H + n0);
        float cnx = sigf(z[1].x) * cv.x + sigf(z[0].x) * tanhf(z[2].x);
        float cny = sigf(z[1].y) * cv.y + sigf(z[0].y) * tanhf(z[2].y);
        float hnx = sigf(z[3].x) * tanhf(cnx);
        float hny = sigf(z[3].y) * tanhf(cny);
        if (quarter == 0) {
            int tp = t_next - 1;
            *(float2*)(cb_nxt + (size_t)b * H + n0) = make_float2(cnx, cny);
            *(float2*)(out_m + ((size_t)tp * B + b) * H + n0) = make_float2(cnx, cny);
            *(float2*)(out_h + ((size_t)b * T + tp) * H + n0) = make_float2(hnx, hny);
            ushort2 hu; hu.x = f2bf(hnx); hu.y = f2bf(hny);
            *(ushort2*)(Abuf + (size_t)b * 1024 + 512 + n0) = hu;
        }
        hp = hnx * w_a_h[n0] + hny * w_a_h[n0 + 1];
    } else {
        ushort2 hu = *(const ushort2*)(Abuf + (size_t)b * 1024 + 512 + n0);
        hp = bf2f(hu.x) * w_a_h[n0] + bf2f(hu.y) * w_a_h[n0 + 1];
    }
    if (t_next >= T) return;

    float s = wred_sum(hp);
    if (lane == 0) red[wid] = s;
    __syncthreads();
    float hs = red[0] + red[1] + red[2] + red[3];
    float scv = (tid < L) ? tanhf(hs + fscore[b * L + tid]) : 0.f;
    float ex = (tid < L) ? expf(scv) : 0.f;   // bounded: scv in [-1,1]
    float es = wred_sum(ex);
    if (lane == 0) red[4 + wid] = es;
    __syncthreads();
    float denom = red[4] + red[5] + red[6] + red[7];
    float al = ex / denom;
    if (tid < L) {
        sal[tid] = al;
        if (quarter == 0) out_a[((size_t)b * T + t_next) * L + tid] = al;
    }
    __syncthreads();

    int fi = tid & 63, lg = tid >> 6;
    const unsigned* xb32 = (const unsigned*)(Xb + (size_t)b * L * F2) + quarter * 64 + fi;
    int l0 = lg * 49;
    float a0 = 0.f, a1 = 0.f;
    {
        unsigned u[25];
        #pragma unroll
        for (int j = 0; j < 25; ++j) u[j] = xb32[(size_t)(l0 + j) * 256];
        #pragma unroll
        for (int j = 0; j < 25; ++j) {
            float w = sal[l0 + j];
            a0 += bf2f((unsigned short)(u[j] & 0xFFFF)) * w;
            a1 += bf2f((unsigned short)(u[j] >> 16)) * w;
        }
    }
    {
        unsigned u[24];
        #pragma unroll
        for (int j = 0; j < 24; ++j) u[j] = xb32[(size_t)(l0 + 25 + j) * 256];
        #pragma unroll
        for (int j = 0; j < 24; ++j) {
            float w = sal[l0 + 25 + j];
            a0 += bf2f((unsigned short)(u[j] & 0xFFFF)) * w;
            a1 += bf2f((unsigned short)(u[j] >> 16)) * w;
        }
    }
    sp2[lg][fi][0] = a0; sp2[lg][fi][1] = a1;
    __syncthreads();
    if (tid < 64) {
        ushort2 cu;
        cu.x = f2bf(sp2[0][tid][0] + sp2[1][tid][0] + sp2[2][tid][0] + sp2[3][tid][0]);
        cu.y = f2bf(sp2[0][tid][1] + sp2[1][tid][1] + sp2[2][tid][1] + sp2[3][tid][1]);
        *(ushort2*)(Abuf + (size_t)b * 1024 + (quarter * 64 + tid) * 2) = cu;
    }
}

extern "C" void kernel_launch(void* const* d_in, const int* in_sizes, int n_in,
                              void* d_out, int out_size, void* d_ws, size_t ws_size,
                              hipStream_t stream) {
    (void)in_sizes; (void)n_in; (void)out_size; (void)ws_size;
    const float* X     = (const float*)d_in[0];
    const float* word  = (const float*)d_in[1];
    const float* w_h   = (const float*)d_in[2];
    const float* b_h   = (const float*)d_in[3];
    const float* w_c   = (const float*)d_in[4];
    const float* b_c   = (const float*)d_in[5];
    const float* w_a_h = (const float*)d_in[6];
    const float* w_a   = (const float*)d_in[7];
    const float* b_a   = (const float*)d_in[8];
    const float* k_w   = (const float*)d_in[9];
    const float* r_w   = (const float*)d_in[10];
    const float* bias  = (const float*)d_in[11];

    float* out_h = (float*)d_out;
    float* out_m = out_h + (size_t)B * T * H;
    float* out_a = out_m + (size_t)T * B * H;

    // ws layout — ~71 MB
    char* p = (char*)d_ws;
    unsigned short* Xb    = (unsigned short*)p; p += (size_t)B * L * F2 * 2;
    unsigned short* WcatT = (unsigned short*)p; p += (size_t)H4 * KCAT * 2;
    unsigned short* wT    = (unsigned short*)p; p += (size_t)H4 * 256 * 2;
    unsigned short* wiT   = (unsigned short*)p; p += (size_t)1024 * 512 * 2;
    unsigned short* fmb   = (unsigned short*)p; p += (size_t)B * F2 * 2;
    unsigned short* Abuf  = (unsigned short*)p; p += (size_t)B * 1024 * 2;
    float* fscore = (float*)p; p += (size_t)B * L * 4;
    float* cb0    = (float*)p; p += (size_t)B * H * 4;
    float* cb1    = (float*)p; p += (size_t)B * H * 4;
    float* zpart  = (float*)p; p += (size_t)KS * B * H4 * 4;
    float* wpart  = (float*)p; p += (size_t)B * T * H4 * 4;
    // fmpart (B*7*512 fp32 = 1.84 MB) aliases zpart (4.19 MB); lifetimes disjoint
    float* fmpart = zpart;

    k_prep2<<<dim3(B, 7), 256, 0, stream>>>(X, w_a, b_a, Xb, fscore, fmpart);
    k_mred<<<B, 256, 0, stream>>>(fmpart, fmb);
    k_trAll<<<dim3(16, 32, 5), 256, 0, stream>>>(k_w, r_w, w_h, w_c, WcatT, wT, wiT);
    k_wi<<<4104, 256, 0, stream>>>(word, wT, wpart, fmb, wiT, b_h, b_c, Abuf, cb0);

    // c_t lives in cb[t&1]; k_wi tail blocks wrote cb0 (= c_0)
    float* cb[2] = {cb0, cb1};
    k_step4<<<dim3(B, 4), 256, 0, stream>>>(zpart, wpart, bias, cb0, cb1, Abuf, Xb,
                                            fscore, w_a_h, out_h, out_m, out_a, 0);
    for (int t = 0; t < T; ++t) {
        k_gemm32<<<512, 256, 0, stream>>>(Abuf, WcatT, zpart);
        k_step4<<<dim3(B, 4), 256, 0, stream>>>(zpart, wpart, bias, cb[t & 1], cb[(t + 1) & 1],
                                                Abuf, Xb, fscore, w_a_h,
                                                out_h, out_m, out_a, t + 1);
    }
}

// Round 17
// 470.252 us; speedup vs baseline: 1.0085x; 1.0085x over previous
//
#include <hip/hip_runtime.h>
#include <math.h>

#define B  128
#define L  196
#define F2 512
#define T  32
#define D  256
#define H  512
#define H4 2048
#define KCAT 1024     // ctx(512) + h(512); word part precomputed
#define KS 4
#define KCHUNK 256    // KCAT/KS

typedef __attribute__((ext_vector_type(8))) short bf16x8;
typedef __attribute__((ext_vector_type(4))) float f32x4;

__device__ __forceinline__ float sigf(float x) { return 1.0f / (1.0f + expf(-x)); }
__device__ __forceinline__ unsigned short f2bf(float x) {
    unsigned u = __float_as_uint(x);
    u += 0x7FFF + ((u >> 16) & 1);
    return (unsigned short)(u >> 16);
}
__device__ __forceinline__ float bf2f(unsigned short s) {
    return __uint_as_float(((unsigned)s) << 16);
}
__device__ __forceinline__ float wred_sum(float v) {
    for (int o = 32; o > 0; o >>= 1) v += __shfl_down(v, o);
    return v;
}

// ---------- setup ----------

__global__ void k_prep2(const float* __restrict__ X, const float* __restrict__ w_a,
                        const float* __restrict__ b_a, unsigned short* __restrict__ Xb,
                        float* __restrict__ fscore, float* __restrict__ fmpart) {
    __shared__ float sp[8][512];
    int b = blockIdx.x, g = blockIdx.y, tid = threadIdx.x;
    int rowi = tid >> 5, lane32 = tid & 31;
    int f0 = tid * 2;
    float2 acc = make_float2(0.f, 0.f);
    for (int s = 0; s < 4; ++s) {
        int li = s * 8 + rowi;
        float4 part[4];
        if (li < 28) {
            size_t row = (size_t)b * L + g * 28 + li;
            const float* src = X + row * F2;
            unsigned short* dst = Xb + row * F2;
            float sc = 0.f;
            #pragma unroll
            for (int j = 0; j < 4; ++j) {
                int f = j * 128 + lane32 * 4;
                float4 v = *(const float4*)(src + f);
                float4 w = *(const float4*)(w_a + f);
                sc += v.x * w.x + v.y * w.y + v.z * w.z + v.w * w.w;
                part[j] = v;
                ushort4 u;
                u.x = f2bf(v.x); u.y = f2bf(v.y); u.z = f2bf(v.z); u.w = f2bf(v.w);
                *(ushort4*)(dst + f) = u;
            }
            for (int o = 16; o > 0; o >>= 1) sc += __shfl_down(sc, o, 32);
            if (lane32 == 0) fscore[row] = sc + b_a[0];
        } else {
            #pragma unroll
            for (int j = 0; j < 4; ++j) part[j] = make_float4(0.f, 0.f, 0.f, 0.f);
        }
        __syncthreads();
        #pragma unroll
        for (int j = 0; j < 4; ++j)
            *(float4*)&sp[rowi][j * 128 + lane32 * 4] = part[j];
        __syncthreads();
        #pragma unroll
        for (int r = 0; r < 8; ++r) { acc.x += sp[r][f0]; acc.y += sp[r][f0 + 1]; }
    }
    *(float2*)&fmpart[((size_t)b * 7 + g) * 512 + f0] = acc;
}

__global__ void k_mred(const float* __restrict__ fmpart, unsigned short* __restrict__ fmb) {
    int b = blockIdx.x, tid = threadIdx.x;
    int f0 = tid * 2;
    float2 acc = make_float2(0.f, 0.f);
    #pragma unroll
    for (int g = 0; g < 7; ++g) {
        float2 v = *(const float2*)&fmpart[((size_t)b * 7 + g) * 512 + f0];
        acc.x += v.x; acc.y += v.y;
    }
    ushort2 u; u.x = f2bf(acc.x * (1.0f / L)); u.y = f2bf(acc.y * (1.0f / L));
    *(ushort2*)(fmb + (size_t)b * F2 + f0) = u;
}

// all 5 transpose-cast jobs in one kernel (byte-exact r15). grid (16, 32, 5).
__global__ void k_trAll(const float* __restrict__ k_w, const float* __restrict__ r_w,
                        const float* __restrict__ w_h, const float* __restrict__ w_c,
                        unsigned short* __restrict__ WcatT, unsigned short* __restrict__ wT,
                        unsigned short* __restrict__ wiT) {
    int job = blockIdx.z;
    if (job == 2 && blockIdx.x >= 8) return;
    if (job >= 3 && blockIdx.y >= 8) return;
    const float* src; unsigned short* dstBase; int srcLD, dstLD, colOff;
    if (job == 0)      { src = k_w + (size_t)256 * H4; dstBase = WcatT; srcLD = H4;  dstLD = KCAT; colOff = 0; }
    else if (job == 1) { src = r_w;  dstBase = WcatT;                   srcLD = H4;  dstLD = KCAT; colOff = 512; }
    else if (job == 2) { src = k_w;  dstBase = wT;                      srcLD = H4;  dstLD = 256;  colOff = 0; }
    else if (job == 3) { src = w_h;  dstBase = wiT;                     srcLD = 512; dstLD = 512;  colOff = 0; }
    else               { src = w_c;  dstBase = wiT + (size_t)512 * 512; srcLD = 512; dstLD = 512;  colOff = 0; }
    __shared__ float Ls[32][65];
    int r0 = blockIdx.x * 32, c0 = blockIdx.y * 64;
    int tid = threadIdx.x;
    int r = tid >> 3, c8 = (tid & 7) * 8;
    const float* s = src + (size_t)(r0 + r) * srcLD + c0 + c8;
    #pragma unroll
    for (int j = 0; j < 8; ++j) Ls[r][c8 + j] = s[j];
    __syncthreads();
    int cc = tid >> 2, q = tid & 3;
    unsigned short tmp[8];
    #pragma unroll
    for (int j = 0; j < 8; ++j) tmp[j] = f2bf(Ls[q * 8 + j][cc]);
    *(float4*)(dstBase + (size_t)(c0 + cc) * dstLD + colOff + r0 + q * 8) = *(float4*)tmp;
}

// ---------- combined one-time GEMMs ----------
// bid < 1024: wgemm 64x128 tiles (r5-verified k_gemm_sep geometry, acc[2][4]);
//   K-chain order identical to r13-r15 -> bit-identical wpart. 4 blocks/CU.
// bid >= 1024: init-state GEMM (8 tail blocks, body byte-exact r15).
__global__ __launch_bounds__(256) void k_wi(
    const float* __restrict__ word,           // [4096][256] fp32
    const unsigned short* __restrict__ wT,    // [2048][256] bf16
    float* __restrict__ wpart,                // [4096][2048] fp32
    const unsigned short* __restrict__ A,     // fm_bf16 [128][512]
    const unsigned short* __restrict__ Bt,    // wiT [1024][512]
    const float* __restrict__ b_h, const float* __restrict__ b_c,
    unsigned short* __restrict__ Abuf0, float* __restrict__ cbuf) {
    __shared__ short As[128 * 64];
    __shared__ short Bs[128 * 64];
    int tid = threadIdx.x;
    int bid = blockIdx.x;
    int wave = tid >> 6, lane = tid & 63;
    int l15 = lane & 15, l4 = lane >> 4;

    if (bid < 1024) {
        // ---- word GEMM: 64x128 tile. M=4096 (64 m-tiles), N=2048 (16 n-tiles), K=256 ----
        int rowbase = (bid >> 4) * 64;
        int nbase = (bid & 15) * 128;
        int wm = (wave & 1) * 32, wn = (wave >> 1) * 64;

        f32x4 acc[2][4];
        #pragma unroll
        for (int i = 0; i < 2; ++i)
            #pragma unroll
            for (int j = 0; j < 4; ++j) acc[i][j] = (f32x4){0.f, 0.f, 0.f, 0.f};

        for (int it = 0; it < 4; ++it) {
            int kbase = it * 64;
            // A: 64 rows x 64 k, fp32 word -> bf16 inline (2 x 8 elems / thread)
            #pragma unroll
            for (int p = 0; p < 2; ++p) {
                int idx = p * 256 + tid;
                int row = idx >> 3, q = idx & 7;
                int k = kbase + q * 8;
                const float* ap = word + (size_t)(rowbase + row) * 256 + k;
                float4 v0 = *(const float4*)ap;
                float4 v1 = *(const float4*)(ap + 4);
                unsigned short tmp[8];
                tmp[0] = f2bf(v0.x); tmp[1] = f2bf(v0.y); tmp[2] = f2bf(v0.z); tmp[3] = f2bf(v0.w);
                tmp[4] = f2bf(v1.x); tmp[5] = f2bf(v1.y); tmp[6] = f2bf(v1.z); tmp[7] = f2bf(v1.w);
                *(float4*)&As[row * 64 + ((q ^ (row & 7)) << 3)] = *(float4*)tmp;
            }
            // B: 128 rows x 64 k from wT (4 x 8 elems / thread)
            #pragma unroll
            for (int p = 0; p < 4; ++p) {
                int idx = p * 256 + tid;
                int row = idx >> 3, q = idx & 7;
                float4 w = *(const float4*)(wT + (size_t)(nbase + row) * 256 + kbase + q * 8);
                *(float4*)&Bs[row * 64 + ((q ^ (row & 7)) << 3)] = w;
            }
            __syncthreads();
            #pragma unroll
            for (int ks2 = 0; ks2 < 2; ++ks2) {
                int q = ks2 * 4 + l4;
                bf16x8 a[2], bb[4];
                #pragma unroll
                for (int fm = 0; fm < 2; ++fm) {
                    int ar = wm + fm * 16 + l15;
                    a[fm] = *(const bf16x8*)&As[ar * 64 + ((q ^ (ar & 7)) << 3)];
                }
                #pragma unroll
                for (int fn = 0; fn < 4; ++fn) {
                    int br = wn + fn * 16 + l15;
                    bb[fn] = *(const bf16x8*)&Bs[br * 64 + ((q ^ (br & 7)) << 3)];
                }
                #pragma unroll
                for (int fm = 0; fm < 2; ++fm)
                    #pragma unroll
                    for (int fn = 0; fn < 4; ++fn)
                        acc[fm][fn] = __builtin_amdgcn_mfma_f32_16x16x32_bf16(a[fm], bb[fn], acc[fm][fn], 0, 0, 0);
            }
            __syncthreads();
        }
        #pragma unroll
        for (int fm = 0; fm < 2; ++fm)
            #pragma unroll
            for (int j = 0; j < 4; ++j) {
                int m = rowbase + wm + fm * 16 + l4 * 4 + j;
                #pragma unroll
                for (int fn = 0; fn < 4; ++fn)
                    wpart[(size_t)m * H4 + nbase + wn + fn * 16 + l15] = acc[fm][fn][j];
            }
        return;
    }

    // ---- init-state GEMM: M=128, K=512, N=1024 (8 tail blocks, byte-exact r15) ----
    int nbase = (bid - 1024) * 128;
    int wm = (wave >> 1) * 64, wn = (wave & 1) * 64;

    f32x4 acc[4][4];
    #pragma unroll
    for (int i = 0; i < 4; ++i)
        #pragma unroll
        for (int j = 0; j < 4; ++j) acc[i][j] = (f32x4){0.f, 0.f, 0.f, 0.f};

    for (int it = 0; it < 8; ++it) {
        int kbase = it * 64;
        #pragma unroll
        for (int ch = 0; ch < 4; ++ch) {
            int idx = ch * 256 + tid;
            int row = idx >> 3, q = idx & 7;
            int k = kbase + q * 8;
            float4 v = *(const float4*)(A + (size_t)row * 512 + k);
            *(float4*)&As[row * 64 + ((q ^ (row & 7)) << 3)] = v;
            float4 w = *(const float4*)(Bt + (size_t)(nbase + row) * 512 + k);
            *(float4*)&Bs[row * 64 + ((q ^ (row & 7)) << 3)] = w;
        }
        __syncthreads();
        #pragma unroll
        for (int ks = 0; ks < 2; ++ks) {
            bf16x8 a[4], b[4];
            #pragma unroll
            for (int f = 0; f < 4; ++f) {
                int ar = wm + f * 16 + l15;
                int q = ks * 4 + l4;
                a[f] = *(const bf16x8*)&As[ar * 64 + ((q ^ (ar & 7)) << 3)];
                int br = wn + f * 16 + l15;
                b[f] = *(const bf16x8*)&Bs[br * 64 + ((q ^ (br & 7)) << 3)];
            }
            #pragma unroll
            for (int fm = 0; fm < 4; ++fm)
                #pragma unroll
                for (int fn = 0; fn < 4; ++fn)
                    acc[fm][fn] = __builtin_amdgcn_mfma_f32_16x16x32_bf16(a[fm], b[fn], acc[fm][fn], 0, 0, 0);
        }
        __syncthreads();
    }
    #pragma unroll
    for (int fm = 0; fm < 4; ++fm)
        #pragma unroll
        for (int j = 0; j < 4; ++j) {
            int m = wm + fm * 16 + l4 * 4 + j;
            #pragma unroll
            for (int fn = 0; fn < 4; ++fn) {
                int gn = nbase + wn + fn * 16 + l15;
                float v = acc[fm][fn][j];
                if (gn < 512) Abuf0[(size_t)m * 1024 + 512 + gn] = f2bf(tanhf(v + b_h[gn]));
                else          cbuf[(size_t)m * 512 + gn - 512] = tanhf(v + b_c[gn - 512]);
            }
        }
}

// ---------- per-step gates GEMM: K=1024, 64x32 tiles, 512 blocks (byte-exact r13-r15) ----------
__global__ __launch_bounds__(256) void k_gemm32(
    const unsigned short* __restrict__ Abuf,
    const unsigned short* __restrict__ WcatT,  // [2048][1024]
    float* __restrict__ zpart) {
    __shared__ short As[64 * 64];
    __shared__ short Bs[32 * 64];
    int tid = threadIdx.x;
    int bid = blockIdx.x;
    int ksb = bid >> 7, rem = bid & 127;
    int rowbase = (rem >> 6) * 64, nbase = (rem & 63) * 32;
    int wave = tid >> 6, lane = tid & 63;
    int wm = (wave & 1) * 32, wn = (wave >> 1) * 16;
    int l15 = lane & 15, l4 = lane >> 4;

    f32x4 acc[2];
    acc[0] = (f32x4){0.f, 0.f, 0.f, 0.f};
    acc[1] = (f32x4){0.f, 0.f, 0.f, 0.f};

    for (int it = 0; it < KCHUNK / 64; ++it) {
        int kbase = ksb * KCHUNK + it * 64;
        #pragma unroll
        for (int p = 0; p < 2; ++p) {
            int idx = p * 256 + tid;
            int row = idx >> 3, q = idx & 7;
            int k = kbase + q * 8;
            float4 v = *(const float4*)(Abuf + (size_t)(rowbase + row) * 1024 + k);
            *(float4*)&As[row * 64 + ((q ^ (row & 7)) << 3)] = v;
        }
        {
            int row = tid >> 3, q = tid & 7;
            float4 w = *(const float4*)(WcatT + (size_t)(nbase + row) * KCAT + kbase + q * 8);
            *(float4*)&Bs[row * 64 + ((q ^ (row & 7)) << 3)] = w;
        }
        __syncthreads();
        #pragma unroll
        for (int ks2 = 0; ks2 < 2; ++ks2) {
            int q = ks2 * 4 + l4;
            bf16x8 a[2], bb;
            #pragma unroll
            for (int fm = 0; fm < 2; ++fm) {
                int ar = wm + fm * 16 + l15;
                a[fm] = *(const bf16x8*)&As[ar * 64 + ((q ^ (ar & 7)) << 3)];
            }
            {
                int br = wn + l15;
                bb = *(const bf16x8*)&Bs[br * 64 + ((q ^ (br & 7)) << 3)];
            }
            #pragma unroll
            for (int fm = 0; fm < 2; ++fm)
                acc[fm] = __builtin_amdgcn_mfma_f32_16x16x32_bf16(a[fm], bb, acc[fm], 0, 0, 0);
        }
        __syncthreads();
    }
    float* zp = zpart + (size_t)ksb * B * H4;
    #pragma unroll
    for (int fm = 0; fm < 2; ++fm)
        #pragma unroll
        for (int j = 0; j < 4; ++j) {
            int m = rowbase + wm + fm * 16 + l4 * 4 + j;
            zp[(size_t)m * H4 + nbase + wn + l15] = acc[fm][j];
        }
}

// ---------- fused cell + attention. grid (B, 4), 256 thr (byte-exact r14/r15) ----------
__global__ __launch_bounds__(256) void k_step4(
    const float* __restrict__ zpart, const float* __restrict__ wpart,
    const float* __restrict__ bias,
    const float* __restrict__ cb_cur, float* __restrict__ cb_nxt,
    unsigned short* __restrict__ Abuf,
    const unsigned short* __restrict__ Xb, const float* __restrict__ fscore,
    const float* __restrict__ w_a_h,
    float* __restrict__ out_h, float* __restrict__ out_m, float* __restrict__ out_a,
    int t_next) {
    __shared__ float red[8];
    __shared__ float sal[200];
    __shared__ float sp2[4][64][2];
    int b = blockIdx.x, quarter = blockIdx.y, tid = threadIdx.x;
    int lane = tid & 63, wid = tid >> 6;
    int n0 = tid * 2;
    float hp;
    if (t_next > 0) {
        const float* wp = wpart + ((size_t)b * T + (t_next - 1)) * H4;
        float2 z[4];
        #pragma unroll
        for (int g = 0; g < 4; ++g) {
            float2 bz = *(const float2*)(bias + g * H + n0);
            float2 wz = *(const float2*)(wp + g * H + n0);
            z[g].x = bz.x + wz.x; z[g].y = bz.y + wz.y;
        }
        #pragma unroll
        for (int ks = 0; ks < KS; ++ks) {
            const float* zp = zpart + ((size_t)ks * B + b) * H4;
            #pragma unroll
            for (int g = 0; g < 4; ++g) {
                float2 v = *(const float2*)(zp + g * H + n0);
                z[g].x += v.x; z[g].y += v.y;
            }
        }
        float2 cv = *(const float2*)(cb_cur + (size_t)b * H + n0);
        float cnx = sigf(z[1].x) * cv.x + sigf(z[0].x) * tanhf(z[2].x);
        float cny = sigf(z[1].y) * cv.y + sigf(z[0].y) * tanhf(z[2].y);
        float hnx = sigf(z[3].x) * tanhf(cnx);
        float hny = sigf(z[3].y) * tanhf(cny);
        if (quarter == 0) {
            int tp = t_next - 1;
            *(float2*)(cb_nxt + (size_t)b * H + n0) = make_float2(cnx, cny);
            *(float2*)(out_m + ((size_t)tp * B + b) * H + n0) = make_float2(cnx, cny);
            *(float2*)(out_h + ((size_t)b * T + tp) * H + n0) = make_float2(hnx, hny);
            ushort2 hu; hu.x = f2bf(hnx); hu.y = f2bf(hny);
            *(ushort2*)(Abuf + (size_t)b * 1024 + 512 + n0) = hu;
        }
        hp = hnx * w_a_h[n0] + hny * w_a_h[n0 + 1];
    } else {
        ushort2 hu = *(const ushort2*)(Abuf + (size_t)b * 1024 + 512 + n0);
        hp = bf2f(hu.x) * w_a_h[n0] + bf2f(hu.y) * w_a_h[n0 + 1];
    }
    if (t_next >= T) return;

    float s = wred_sum(hp);
    if (lane == 0) red[wid] = s;
    __syncthreads();
    float hs = red[0] + red[1] + red[2] + red[3];
    float scv = (tid < L) ? tanhf(hs + fscore[b * L + tid]) : 0.f;
    float ex = (tid < L) ? expf(scv) : 0.f;   // bounded: scv in [-1,1]
    float es = wred_sum(ex);
    if (lane == 0) red[4 + wid] = es;
    __syncthreads();
    float denom = red[4] + red[5] + red[6] + red[7];
    float al = ex / denom;
    if (tid < L) {
        sal[tid] = al;
        if (quarter == 0) out_a[((size_t)b * T + t_next) * L + tid] = al;
    }
    __syncthreads();

    int fi = tid & 63, lg = tid >> 6;
    const unsigned* xb32 = (const unsigned*)(Xb + (size_t)b * L * F2) + quarter * 64 + fi;
    int l0 = lg * 49;
    float a0 = 0.f, a1 = 0.f;
    {
        unsigned u[25];
        #pragma unroll
        for (int j = 0; j < 25; ++j) u[j] = xb32[(size_t)(l0 + j) * 256];
        #pragma unroll
        for (int j = 0; j < 25; ++j) {
            float w = sal[l0 + j];
            a0 += bf2f((unsigned short)(u[j] & 0xFFFF)) * w;
            a1 += bf2f((unsigned short)(u[j] >> 16)) * w;
        }
    }
    {
        unsigned u[24];
        #pragma unroll
        for (int j = 0; j < 24; ++j) u[j] = xb32[(size_t)(l0 + 25 + j) * 256];
        #pragma unroll
        for (int j = 0; j < 24; ++j) {
            float w = sal[l0 + 25 + j];
            a0 += bf2f((unsigned short)(u[j] & 0xFFFF)) * w;
            a1 += bf2f((unsigned short)(u[j] >> 16)) * w;
        }
    }
    sp2[lg][fi][0] = a0; sp2[lg][fi][1] = a1;
    __syncthreads();
    if (tid < 64) {
        ushort2 cu;
        cu.x = f2bf(sp2[0][tid][0] + sp2[1][tid][0] + sp2[2][tid][0] + sp2[3][tid][0]);
        cu.y = f2bf(sp2[0][tid][1] + sp2[1][tid][1] + sp2[2][tid][1] + sp2[3][tid][1]);
        *(ushort2*)(Abuf + (size_t)b * 1024 + (quarter * 64 + tid) * 2) = cu;
    }
}

extern "C" void kernel_launch(void* const* d_in, const int* in_sizes, int n_in,
                              void* d_out, int out_size, void* d_ws, size_t ws_size,
                              hipStream_t stream) {
    (void)in_sizes; (void)n_in; (void)out_size; (void)ws_size;
    const float* X     = (const float*)d_in[0];
    const float* word  = (const float*)d_in[1];
    const float* w_h   = (const float*)d_in[2];
    const float* b_h   = (const float*)d_in[3];
    const float* w_c   = (const float*)d_in[4];
    const float* b_c   = (const float*)d_in[5];
    const float* w_a_h = (const float*)d_in[6];
    const float* w_a   = (const float*)d_in[7];
    const float* b_a   = (const float*)d_in[8];
    const float* k_w   = (const float*)d_in[9];
    const float* r_w   = (const float*)d_in[10];
    const float* bias  = (const float*)d_in[11];

    float* out_h = (float*)d_out;
    float* out_m = out_h + (size_t)B * T * H;
    float* out_a = out_m + (size_t)T * B * H;

    // ws layout — ~71 MB
    char* p = (char*)d_ws;
    unsigned short* Xb    = (unsigned short*)p; p += (size_t)B * L * F2 * 2;
    unsigned short* WcatT = (unsigned short*)p; p += (size_t)H4 * KCAT * 2;
    unsigned short* wT    = (unsigned short*)p; p += (size_t)H4 * 256 * 2;
    unsigned short* wiT   = (unsigned short*)p; p += (size_t)1024 * 512 * 2;
    unsigned short* fmb   = (unsigned short*)p; p += (size_t)B * F2 * 2;
    unsigned short* Abuf  = (unsigned short*)p; p += (size_t)B * 1024 * 2;
    float* fscore = (float*)p; p += (size_t)B * L * 4;
    float* cb0    = (float*)p; p += (size_t)B * H * 4;
    float* cb1    = (float*)p; p += (size_t)B * H * 4;
    float* zpart  = (float*)p; p += (size_t)KS * B * H4 * 4;
    float* wpart  = (float*)p; p += (size_t)B * T * H4 * 4;
    // fmpart (B*7*512 fp32 = 1.84 MB) aliases zpart (4.19 MB); lifetimes disjoint
    float* fmpart = zpart;

    k_prep2<<<dim3(B, 7), 256, 0, stream>>>(X, w_a, b_a, Xb, fscore, fmpart);
    k_mred<<<B, 256, 0, stream>>>(fmpart, fmb);
    k_trAll<<<dim3(16, 32, 5), 256, 0, stream>>>(k_w, r_w, w_h, w_c, WcatT, wT, wiT);
    k_wi<<<1032, 256, 0, stream>>>(word, wT, wpart, fmb, wiT, b_h, b_c, Abuf, cb0);

    // c_t lives in cb[t&1]; k_wi tail blocks wrote cb0 (= c_0)
    float* cb[2] = {cb0, cb1};
    k_step4<<<dim3(B, 4), 256, 0, stream>>>(zpart, wpart, bias, cb0, cb1, Abuf, Xb,
                                            fscore, w_a_h, out_h, out_m, out_a, 0);
    for (int t = 0; t < T; ++t) {
        k_gemm32<<<512, 256, 0, stream>>>(Abuf, WcatT, zpart);
        k_step4<<<dim3(B, 4), 256, 0, stream>>>(zpart, wpart, bias, cb[t & 1], cb[(t + 1) & 1],
                                                Abuf, Xb, fscore, w_a_h,
                                                out_h, out_m, out_a, t + 1);
    }
}

// Round 18
// 451.054 us; speedup vs baseline: 1.0514x; 1.0426x over previous
//
#include <hip/hip_runtime.h>
#include <math.h>

#define B  128
#define L  196
#define F2 512
#define T  32
#define D  256
#define H  512
#define H4 2048
#define KCAT 1024     // ctx(512) + h(512); word part precomputed
#define KS 4
#define KCHUNK 256    // KCAT/KS

typedef __attribute__((ext_vector_type(8))) short bf16x8;
typedef __attribute__((ext_vector_type(4))) float f32x4;

__device__ __forceinline__ float sigf(float x) { return 1.0f / (1.0f + expf(-x)); }
__device__ __forceinline__ unsigned short f2bf(float x) {
    unsigned u = __float_as_uint(x);
    u += 0x7FFF + ((u >> 16) & 1);
    return (unsigned short)(u >> 16);
}
__device__ __forceinline__ float bf2f(unsigned short s) {
    return __uint_as_float(((unsigned)s) << 16);
}
__device__ __forceinline__ float wred_sum(float v) {
    for (int o = 32; o > 0; o >>= 1) v += __shfl_down(v, o);
    return v;
}

// ---------- setup ----------

__global__ void k_prep2(const float* __restrict__ X, const float* __restrict__ w_a,
                        const float* __restrict__ b_a, unsigned short* __restrict__ Xb,
                        float* __restrict__ fscore, float* __restrict__ fmpart) {
    __shared__ float sp[8][512];
    int b = blockIdx.x, g = blockIdx.y, tid = threadIdx.x;
    int rowi = tid >> 5, lane32 = tid & 31;
    int f0 = tid * 2;
    float2 acc = make_float2(0.f, 0.f);
    for (int s = 0; s < 4; ++s) {
        int li = s * 8 + rowi;
        float4 part[4];
        if (li < 28) {
            size_t row = (size_t)b * L + g * 28 + li;
            const float* src = X + row * F2;
            unsigned short* dst = Xb + row * F2;
            float sc = 0.f;
            #pragma unroll
            for (int j = 0; j < 4; ++j) {
                int f = j * 128 + lane32 * 4;
                float4 v = *(const float4*)(src + f);
                float4 w = *(const float4*)(w_a + f);
                sc += v.x * w.x + v.y * w.y + v.z * w.z + v.w * w.w;
                part[j] = v;
                ushort4 u;
                u.x = f2bf(v.x); u.y = f2bf(v.y); u.z = f2bf(v.z); u.w = f2bf(v.w);
                *(ushort4*)(dst + f) = u;
            }
            for (int o = 16; o > 0; o >>= 1) sc += __shfl_down(sc, o, 32);
            if (lane32 == 0) fscore[row] = sc + b_a[0];
        } else {
            #pragma unroll
            for (int j = 0; j < 4; ++j) part[j] = make_float4(0.f, 0.f, 0.f, 0.f);
        }
        __syncthreads();
        #pragma unroll
        for (int j = 0; j < 4; ++j)
            *(float4*)&sp[rowi][j * 128 + lane32 * 4] = part[j];
        __syncthreads();
        #pragma unroll
        for (int r = 0; r < 8; ++r) { acc.x += sp[r][f0]; acc.y += sp[r][f0 + 1]; }
    }
    *(float2*)&fmpart[((size_t)b * 7 + g) * 512 + f0] = acc;
}

__global__ void k_mred(const float* __restrict__ fmpart, unsigned short* __restrict__ fmb) {
    int b = blockIdx.x, tid = threadIdx.x;
    int f0 = tid * 2;
    float2 acc = make_float2(0.f, 0.f);
    #pragma unroll
    for (int g = 0; g < 7; ++g) {
        float2 v = *(const float2*)&fmpart[((size_t)b * 7 + g) * 512 + f0];
        acc.x += v.x; acc.y += v.y;
    }
    ushort2 u; u.x = f2bf(acc.x * (1.0f / L)); u.y = f2bf(acc.y * (1.0f / L));
    *(ushort2*)(fmb + (size_t)b * F2 + f0) = u;
}

// all 5 transpose-cast jobs in one kernel. grid (16, 32, 5), 256 thr.
__global__ void k_trAll(const float* __restrict__ k_w, const float* __restrict__ r_w,
                        const float* __restrict__ w_h, const float* __restrict__ w_c,
                        unsigned short* __restrict__ WcatT, unsigned short* __restrict__ wT,
                        unsigned short* __restrict__ wiT) {
    int job = blockIdx.z;
    if (job == 2 && blockIdx.x >= 8) return;
    if (job >= 3 && blockIdx.y >= 8) return;
    const float* src; unsigned short* dstBase; int srcLD, dstLD, colOff;
    if (job == 0)      { src = k_w + (size_t)256 * H4; dstBase = WcatT; srcLD = H4;  dstLD = KCAT; colOff = 0; }
    else if (job == 1) { src = r_w;  dstBase = WcatT;                   srcLD = H4;  dstLD = KCAT; colOff = 512; }
    else if (job == 2) { src = k_w;  dstBase = wT;                      srcLD = H4;  dstLD = 256;  colOff = 0; }
    else if (job == 3) { src = w_h;  dstBase = wiT;                     srcLD = 512; dstLD = 512;  colOff = 0; }
    else               { src = w_c;  dstBase = wiT + (size_t)512 * 512; srcLD = 512; dstLD = 512;  colOff = 0; }
    __shared__ float Ls[32][65];
    int r0 = blockIdx.x * 32, c0 = blockIdx.y * 64;
    int tid = threadIdx.x;
    int r = tid >> 3, c8 = (tid & 7) * 8;
    const float* s = src + (size_t)(r0 + r) * srcLD + c0 + c8;
    #pragma unroll
    for (int j = 0; j < 8; ++j) Ls[r][c8 + j] = s[j];
    __syncthreads();
    int cc = tid >> 2, q = tid & 3;
    unsigned short tmp[8];
    #pragma unroll
    for (int j = 0; j < 8; ++j) tmp[j] = f2bf(Ls[q * 8 + j][cc]);
    *(float4*)(dstBase + (size_t)(c0 + cc) * dstLD + colOff + r0 + q * 8) = *(float4*)tmp;
}

// ---------- combined one-time GEMMs: z=0 wgemm (16x32 tiles), z=1 init_gemm (8 tiles) ----------
__global__ __launch_bounds__(256) void k_wi(
    const float* __restrict__ word,           // [4096][256] fp32
    const unsigned short* __restrict__ wT,    // [2048][256] bf16
    float* __restrict__ wpart,                // [4096][2048] fp32
    const unsigned short* __restrict__ A,     // fm_bf16 [128][512]
    const unsigned short* __restrict__ Bt,    // wiT [1024][512]
    const float* __restrict__ b_h, const float* __restrict__ b_c,
    unsigned short* __restrict__ Abuf0, float* __restrict__ cbuf) {
    __shared__ short As[128 * 64];
    __shared__ short Bs[128 * 64];
    int tid = threadIdx.x;
    int wave = tid >> 6, lane = tid & 63;
    int wm = (wave >> 1) * 64, wn = (wave & 1) * 64;
    int l15 = lane & 15, l4 = lane >> 4;

    f32x4 acc[4][4];
    #pragma unroll
    for (int i = 0; i < 4; ++i)
        #pragma unroll
        for (int j = 0; j < 4; ++j) acc[i][j] = (f32x4){0.f, 0.f, 0.f, 0.f};

    if (blockIdx.z == 1) {
        // ---- init-state GEMM: M=128, K=512, N=1024 ----
        if (blockIdx.x >= 8 || blockIdx.y != 0) return;
        int nbase = blockIdx.x * 128;
        for (int it = 0; it < 8; ++it) {
            int kbase = it * 64;
            #pragma unroll
            for (int ch = 0; ch < 4; ++ch) {
                int idx = ch * 256 + tid;
                int row = idx >> 3, q = idx & 7;
                int k = kbase + q * 8;
                float4 v = *(const float4*)(A + (size_t)row * 512 + k);
                *(float4*)&As[row * 64 + ((q ^ (row & 7)) << 3)] = v;
                float4 w = *(const float4*)(Bt + (size_t)(nbase + row) * 512 + k);
                *(float4*)&Bs[row * 64 + ((q ^ (row & 7)) << 3)] = w;
            }
            __syncthreads();
            #pragma unroll
            for (int ks = 0; ks < 2; ++ks) {
                bf16x8 a[4], b[4];
                #pragma unroll
                for (int f = 0; f < 4; ++f) {
                    int ar = wm + f * 16 + l15;
                    int q = ks * 4 + l4;
                    a[f] = *(const bf16x8*)&As[ar * 64 + ((q ^ (ar & 7)) << 3)];
                    int br = wn + f * 16 + l15;
                    b[f] = *(const bf16x8*)&Bs[br * 64 + ((q ^ (br & 7)) << 3)];
                }
                #pragma unroll
                for (int fm = 0; fm < 4; ++fm)
                    #pragma unroll
                    for (int fn = 0; fn < 4; ++fn)
                        acc[fm][fn] = __builtin_amdgcn_mfma_f32_16x16x32_bf16(a[fm], b[fn], acc[fm][fn], 0, 0, 0);
            }
            __syncthreads();
        }
        #pragma unroll
        for (int fm = 0; fm < 4; ++fm)
            #pragma unroll
            for (int j = 0; j < 4; ++j) {
                int m = wm + fm * 16 + l4 * 4 + j;
                #pragma unroll
                for (int fn = 0; fn < 4; ++fn) {
                    int gn = nbase + wn + fn * 16 + l15;
                    float v = acc[fm][fn][j];
                    if (gn < 512) Abuf0[(size_t)m * 1024 + 512 + gn] = f2bf(tanhf(v + b_h[gn]));
                    else          cbuf[(size_t)m * 512 + gn - 512] = tanhf(v + b_c[gn - 512]);
                }
            }
        return;
    }

    // ---- word GEMM: wpart = bf16(word) @ wT^T.  M=4096, K=256, N=2048 ----
    int nbase = blockIdx.x * 128;
    int mbase = blockIdx.y * 128;
    for (int it = 0; it < 4; ++it) {
        int kbase = it * 64;
        #pragma unroll
        for (int ch = 0; ch < 4; ++ch) {
            int idx = ch * 256 + tid;
            int row = idx >> 3, q = idx & 7;
            int k = kbase + q * 8;
            const float* ap = word + (size_t)(mbase + row) * 256 + k;
            float4 v0 = *(const float4*)ap;
            float4 v1 = *(const float4*)(ap + 4);
            unsigned short tmp[8];
            tmp[0] = f2bf(v0.x); tmp[1] = f2bf(v0.y); tmp[2] = f2bf(v0.z); tmp[3] = f2bf(v0.w);
            tmp[4] = f2bf(v1.x); tmp[5] = f2bf(v1.y); tmp[6] = f2bf(v1.z); tmp[7] = f2bf(v1.w);
            *(float4*)&As[row * 64 + ((q ^ (row & 7)) << 3)] = *(float4*)tmp;
            float4 w = *(const float4*)(wT + (size_t)(nbase + row) * 256 + k);
            *(float4*)&Bs[row * 64 + ((q ^ (row & 7)) << 3)] = w;
        }
        __syncthreads();
        #pragma unroll
        for (int ks = 0; ks < 2; ++ks) {
            bf16x8 a[4], b[4];
            #pragma unroll
            for (int f = 0; f < 4; ++f) {
                int ar = wm + f * 16 + l15;
                int q = ks * 4 + l4;
                a[f] = *(const bf16x8*)&As[ar * 64 + ((q ^ (ar & 7)) << 3)];
                int br = wn + f * 16 + l15;
                b[f] = *(const bf16x8*)&Bs[br * 64 + ((q ^ (br & 7)) << 3)];
            }
            #pragma unroll
            for (int fm = 0; fm < 4; ++fm)
                #pragma unroll
                for (int fn = 0; fn < 4; ++fn)
                    acc[fm][fn] = __builtin_amdgcn_mfma_f32_16x16x32_bf16(a[fm], b[fn], acc[fm][fn], 0, 0, 0);
        }
        __syncthreads();
    }
    #pragma unroll
    for (int fm = 0; fm < 4; ++fm)
        #pragma unroll
        for (int j = 0; j < 4; ++j) {
            int m = wm + fm * 16 + l4 * 4 + j;
            #pragma unroll
            for (int fn = 0; fn < 4; ++fn)
                wpart[(size_t)(mbase + m) * H4 + nbase + wn + fn * 16 + l15] = acc[fm][fn][j];
        }
}

// ---------- per-step gates GEMM: K=1024, 64x32 tiles, 512 blocks (byte-exact r13-r15) ----------
__global__ __launch_bounds__(256) void k_gemm32(
    const unsigned short* __restrict__ Abuf,
    const unsigned short* __restrict__ WcatT,  // [2048][1024]
    float* __restrict__ zpart) {
    __shared__ short As[64 * 64];
    __shared__ short Bs[32 * 64];
    int tid = threadIdx.x;
    int bid = blockIdx.x;
    int ksb = bid >> 7, rem = bid & 127;
    int rowbase = (rem >> 6) * 64, nbase = (rem & 63) * 32;
    int wave = tid >> 6, lane = tid & 63;
    int wm = (wave & 1) * 32, wn = (wave >> 1) * 16;
    int l15 = lane & 15, l4 = lane >> 4;

    f32x4 acc[2];
    acc[0] = (f32x4){0.f, 0.f, 0.f, 0.f};
    acc[1] = (f32x4){0.f, 0.f, 0.f, 0.f};

    for (int it = 0; it < KCHUNK / 64; ++it) {
        int kbase = ksb * KCHUNK + it * 64;
        #pragma unroll
        for (int p = 0; p < 2; ++p) {
            int idx = p * 256 + tid;
            int row = idx >> 3, q = idx & 7;
            int k = kbase + q * 8;
            float4 v = *(const float4*)(Abuf + (size_t)(rowbase + row) * 1024 + k);
            *(float4*)&As[row * 64 + ((q ^ (row & 7)) << 3)] = v;
        }
        {
            int row = tid >> 3, q = tid & 7;
            float4 w = *(const float4*)(WcatT + (size_t)(nbase + row) * KCAT + kbase + q * 8);
            *(float4*)&Bs[row * 64 + ((q ^ (row & 7)) << 3)] = w;
        }
        __syncthreads();
        #pragma unroll
        for (int ks2 = 0; ks2 < 2; ++ks2) {
            int q = ks2 * 4 + l4;
            bf16x8 a[2], bb;
            #pragma unroll
            for (int fm = 0; fm < 2; ++fm) {
                int ar = wm + fm * 16 + l15;
                a[fm] = *(const bf16x8*)&As[ar * 64 + ((q ^ (ar & 7)) << 3)];
            }
            {
                int br = wn + l15;
                bb = *(const bf16x8*)&Bs[br * 64 + ((q ^ (br & 7)) << 3)];
            }
            #pragma unroll
            for (int fm = 0; fm < 2; ++fm)
                acc[fm] = __builtin_amdgcn_mfma_f32_16x16x32_bf16(a[fm], bb, acc[fm], 0, 0, 0);
        }
        __syncthreads();
    }
    float* zp = zpart + (size_t)ksb * B * H4;
    #pragma unroll
    for (int fm = 0; fm < 2; ++fm)
        #pragma unroll
        for (int j = 0; j < 4; ++j) {
            int m = rowbase + wm + fm * 16 + l4 * 4 + j;
            zp[(size_t)m * H4 + nbase + wn + l15] = acc[fm][j];
        }
}

// ---------- fused cell + attention. grid (B, 4), 256 thr (byte-exact r14/r15) ----------
__global__ __launch_bounds__(256) void k_step4(
    const float* __restrict__ zpart, const float* __restrict__ wpart,
    const float* __restrict__ bias,
    const float* __restrict__ cb_cur, float* __restrict__ cb_nxt,
    unsigned short* __restrict__ Abuf,
    const unsigned short* __restrict__ Xb, const float* __restrict__ fscore,
    const float* __restrict__ w_a_h,
    float* __restrict__ out_h, float* __restrict__ out_m, float* __restrict__ out_a,
    int t_next) {
    __shared__ float red[8];
    __shared__ float sal[200];
    __shared__ float sp2[4][64][2];
    int b = blockIdx.x, quarter = blockIdx.y, tid = threadIdx.x;
    int lane = tid & 63, wid = tid >> 6;
    int n0 = tid * 2;
    float hp;
    if (t_next > 0) {
        const float* wp = wpart + ((size_t)b * T + (t_next - 1)) * H4;
        float2 z[4];
        #pragma unroll
        for (int g = 0; g < 4; ++g) {
            float2 bz = *(const float2*)(bias + g * H + n0);
            float2 wz = *(const float2*)(wp + g * H + n0);
            z[g].x = bz.x + wz.x; z[g].y = bz.y + wz.y;
        }
        #pragma unroll
        for (int ks = 0; ks < KS; ++ks) {
            const float* zp = zpart + ((size_t)ks * B + b) * H4;
            #pragma unroll
            for (int g = 0; g < 4; ++g) {
                float2 v = *(const float2*)(zp + g * H + n0);
                z[g].x += v.x; z[g].y += v.y;
            }
        }
        float2 cv = *(const float2*)(cb_cur + (size_t)b * H + n0);
        float cnx = sigf(z[1].x) * cv.x + sigf(z[0].x) * tanhf(z[2].x);
        float cny = sigf(z[1].y) * cv.y + sigf(z[0].y) * tanhf(z[2].y);
        float hnx = sigf(z[3].x) * tanhf(cnx);
        float hny = sigf(z[3].y) * tanhf(cny);
        if (quarter == 0) {
            int tp = t_next - 1;
            *(float2*)(cb_nxt + (size_t)b * H + n0) = make_float2(cnx, cny);
            *(float2*)(out_m + ((size_t)tp * B + b) * H + n0) = make_float2(cnx, cny);
            *(float2*)(out_h + ((size_t)b * T + tp) * H + n0) = make_float2(hnx, hny);
            ushort2 hu; hu.x = f2bf(hnx); hu.y = f2bf(hny);
            *(ushort2*)(Abuf + (size_t)b * 1024 + 512 + n0) = hu;
        }
        hp = hnx * w_a_h[n0] + hny * w_a_h[n0 + 1];
    } else {
        ushort2 hu = *(const ushort2*)(Abuf + (size_t)b * 1024 + 512 + n0);
        hp = bf2f(hu.x) * w_a_h[n0] + bf2f(hu.y) * w_a_h[n0 + 1];
    }
    if (t_next >= T) return;

    float s = wred_sum(hp);
    if (lane == 0) red[wid] = s;
    __syncthreads();
    float hs = red[0] + red[1] + red[2] + red[3];
    float scv = (tid < L) ? tanhf(hs + fscore[b * L + tid]) : 0.f;
    float ex = (tid < L) ? expf(scv) : 0.f;   // bounded: scv in [-1,1]
    float es = wred_sum(ex);
    if (lane == 0) red[4 + wid] = es;
    __syncthreads();
    float denom = red[4] + red[5] + red[6] + red[7];
    float al = ex / denom;
    if (tid < L) {
        sal[tid] = al;
        if (quarter == 0) out_a[((size_t)b * T + t_next) * L + tid] = al;
    }
    __syncthreads();

    int fi = tid & 63, lg = tid >> 6;
    const unsigned* xb32 = (const unsigned*)(Xb + (size_t)b * L * F2) + quarter * 64 + fi;
    int l0 = lg * 49;
    float a0 = 0.f, a1 = 0.f;
    {
        unsigned u[25];
        #pragma unroll
        for (int j = 0; j < 25; ++j) u[j] = xb32[(size_t)(l0 + j) * 256];
        #pragma unroll
        for (int j = 0; j < 25; ++j) {
            float w = sal[l0 + j];
            a0 += bf2f((unsigned short)(u[j] & 0xFFFF)) * w;
            a1 += bf2f((unsigned short)(u[j] >> 16)) * w;
        }
    }
    {
        unsigned u[24];
        #pragma unroll
        for (int j = 0; j < 24; ++j) u[j] = xb32[(size_t)(l0 + 25 + j) * 256];
        #pragma unroll
        for (int j = 0; j < 24; ++j) {
            float w = sal[l0 + 25 + j];
            a0 += bf2f((unsigned short)(u[j] & 0xFFFF)) * w;
            a1 += bf2f((unsigned short)(u[j] >> 16)) * w;
        }
    }
    sp2[lg][fi][0] = a0; sp2[lg][fi][1] = a1;
    __syncthreads();
    if (tid < 64) {
        ushort2 cu;
        cu.x = f2bf(sp2[0][tid][0] + sp2[1][tid][0] + sp2[2][tid][0] + sp2[3][tid][0]);
        cu.y = f2bf(sp2[0][tid][1] + sp2[1][tid][1] + sp2[2][tid][1] + sp2[3][tid][1]);
        *(ushort2*)(Abuf + (size_t)b * 1024 + (quarter * 64 + tid) * 2) = cu;
    }
}

extern "C" void kernel_launch(void* const* d_in, const int* in_sizes, int n_in,
                              void* d_out, int out_size, void* d_ws, size_t ws_size,
                              hipStream_t stream) {
    (void)in_sizes; (void)n_in; (void)out_size; (void)ws_size;
    const float* X     = (const float*)d_in[0];
    const float* word  = (const float*)d_in[1];
    const float* w_h   = (const float*)d_in[2];
    const float* b_h   = (const float*)d_in[3];
    const float* w_c   = (const float*)d_in[4];
    const float* b_c   = (const float*)d_in[5];
    const float* w_a_h = (const float*)d_in[6];
    const float* w_a   = (const float*)d_in[7];
    const float* b_a   = (const float*)d_in[8];
    const float* k_w   = (const float*)d_in[9];
    const float* r_w   = (const float*)d_in[10];
    const float* bias  = (const float*)d_in[11];

    float* out_h = (float*)d_out;
    float* out_m = out_h + (size_t)B * T * H;
    float* out_a = out_m + (size_t)T * B * H;

    // ws layout — ~71 MB
    char* p = (char*)d_ws;
    unsigned short* Xb    = (unsigned short*)p; p += (size_t)B * L * F2 * 2;
    unsigned short* WcatT = (unsigned short*)p; p += (size_t)H4 * KCAT * 2;
    unsigned short* wT    = (unsigned short*)p; p += (size_t)H4 * 256 * 2;
    unsigned short* wiT   = (unsigned short*)p; p += (size_t)1024 * 512 * 2;
    unsigned short* fmb   = (unsigned short*)p; p += (size_t)B * F2 * 2;
    unsigned short* Abuf  = (unsigned short*)p; p += (size_t)B * 1024 * 2;
    float* fscore = (float*)p; p += (size_t)B * L * 4;
    float* cb0    = (float*)p; p += (size_t)B * H * 4;
    float* cb1    = (float*)p; p += (size_t)B * H * 4;
    float* zpart  = (float*)p; p += (size_t)KS * B * H4 * 4;
    float* wpart  = (float*)p; p += (size_t)B * T * H4 * 4;
    // fmpart (B*7*512 fp32 = 1.84 MB) aliases zpart (4.19 MB); lifetimes disjoint
    float* fmpart = zpart;

    k_prep2<<<dim3(B, 7), 256, 0, stream>>>(X, w_a, b_a, Xb, fscore, fmpart);
    k_mred<<<B, 256, 0, stream>>>(fmpart, fmb);
    k_trAll<<<dim3(16, 32, 5), 256, 0, stream>>>(k_w, r_w, w_h, w_c, WcatT, wT, wiT);
    k_wi<<<dim3(16, 32, 2), 256, 0, stream>>>(word, wT, wpart, fmb, wiT, b_h, b_c, Abuf, cb0);

    // c_t lives in cb[t&1]; k_wi (z=1) wrote cb0 (= c_0)
    float* cb[2] = {cb0, cb1};
    k_step4<<<dim3(B, 4), 256, 0, stream>>>(zpart, wpart, bias, cb0, cb1, Abuf, Xb,
                                            fscore, w_a_h, out_h, out_m, out_a, 0);
    for (int t = 0; t < T; ++t) {
        k_gemm32<<<512, 256, 0, stream>>>(Abuf, WcatT, zpart);
        k_step4<<<dim3(B, 4), 256, 0, stream>>>(zpart, wpart, bias, cb[t & 1], cb[(t + 1) & 1],
                                                Abuf, Xb, fscore, w_a_h,
                                                out_h, out_m, out_a, t + 1);
    }
}